// Round 9
// baseline (15374.333 us; speedup 1.0000x reference)
//
#include <hip/hip_runtime.h>

#define SEQ 8192
#define H 1024

// ---------------------------------------------------------------------------
// Projection GEMM (NT): C[i][j] = bias[j] + sum_k A[i][k]*B[j][k]
// (unchanged — ~0.6 ms, not the bottleneck)
// ---------------------------------------------------------------------------
#define KC 32
#define LDT 68

__global__ __launch_bounds__(256) void proj_gemm(
    const float* __restrict__ A,
    const float* __restrict__ B0, const float* __restrict__ b0, float* __restrict__ C0,
    const float* __restrict__ B1, const float* __restrict__ b1, float* __restrict__ C1,
    const float* __restrict__ B2, const float* __restrict__ b2, float* __restrict__ C2)
{
    __shared__ __align__(16) float As[KC * LDT];
    __shared__ __align__(16) float Bs[KC * LDT];

    const float* Bm; const float* bias; float* C;
    if (blockIdx.z == 0)      { Bm = B0; bias = b0; C = C0; }
    else if (blockIdx.z == 1) { Bm = B1; bias = b1; C = C1; }
    else                      { Bm = B2; bias = b2; C = C2; }

    const int j0 = blockIdx.x * 64;
    const int i0 = blockIdx.y * 64;
    const int tid = threadIdx.x;
    const int tx = tid & 15, ty = tid >> 4;
    const int lrow = tid >> 3;
    const int lkq  = tid & 7;

    float acc[4][4];
#pragma unroll
    for (int r = 0; r < 4; r++)
#pragma unroll
        for (int c = 0; c < 4; c++) acc[r][c] = 0.f;

    for (int k0 = 0; k0 < H; k0 += KC) {
#pragma unroll
        for (int half = 0; half < 2; half++) {
            const int row = lrow + half * 32;
            float4 a = *(const float4*)&A[(size_t)(i0 + row) * H + k0 + 4 * lkq];
            As[(4 * lkq + 0) * LDT + row] = a.x;
            As[(4 * lkq + 1) * LDT + row] = a.y;
            As[(4 * lkq + 2) * LDT + row] = a.z;
            As[(4 * lkq + 3) * LDT + row] = a.w;
            float4 b = *(const float4*)&Bm[(size_t)(j0 + row) * H + k0 + 4 * lkq];
            Bs[(4 * lkq + 0) * LDT + row] = b.x;
            Bs[(4 * lkq + 1) * LDT + row] = b.y;
            Bs[(4 * lkq + 2) * LDT + row] = b.z;
            Bs[(4 * lkq + 3) * LDT + row] = b.w;
        }
        __syncthreads();
#pragma unroll
        for (int k = 0; k < KC; k++) {
            float4 a4 = *(const float4*)&As[k * LDT + ty * 4];
            float4 b4 = *(const float4*)&Bs[k * LDT + tx * 4];
            acc[0][0] += a4.x * b4.x; acc[0][1] += a4.x * b4.y;
            acc[0][2] += a4.x * b4.z; acc[0][3] += a4.x * b4.w;
            acc[1][0] += a4.y * b4.x; acc[1][1] += a4.y * b4.y;
            acc[1][2] += a4.y * b4.z; acc[1][3] += a4.y * b4.w;
            acc[2][0] += a4.z * b4.x; acc[2][1] += a4.z * b4.y;
            acc[2][2] += a4.z * b4.z; acc[2][3] += a4.z * b4.w;
            acc[3][0] += a4.w * b4.x; acc[3][1] += a4.w * b4.y;
            acc[3][2] += a4.w * b4.z; acc[3][3] += a4.w * b4.w;
        }
        __syncthreads();
    }

    float4 bi = *(const float4*)&bias[j0 + tx * 4];
#pragma unroll
    for (int r = 0; r < 4; r++) {
        float4 o;
        o.x = acc[r][0] + bi.x; o.y = acc[r][1] + bi.y;
        o.z = acc[r][2] + bi.z; o.w = acc[r][3] + bi.w;
        *(float4*)&C[(size_t)(i0 + ty * 4 + r) * H + j0 + tx * 4] = o;
    }
}

// ---------------------------------------------------------------------------
// GRU scan v8 = v6 (weights in LDS, proven 13.5 ms) + staggered depth-2 poll
// with the barrier drain REMOVED.
//   v7 post-mortem: __syncthreads() emits `s_waitcnt vmcnt(0)` before
//   s_barrier -> the 2 dangling staggered loads (issued ~RT/2 before break)
//   were drained AT the barrier, +~350cy/step on every wave's path; the
//   sampling gain (~250cy) couldn't pay for it -> v7's +1ms. The sampling
//   theory was not falsified; the implementation collided with the
//   implicit drain.
//   v8 fix (T3/T4 counted-vmcnt idiom):
//     - raw `__builtin_amdgcn_s_barrier()` preceded by asm
//       `s_waitcnt lgkmcnt(0)` (hb ds_writes visible to other waves) +
//       sched_barrier(0). Dangling VMEM loads legally cross the barrier.
//     - end-of-iteration drain is `s_waitcnt vmcnt(2)` AFTER the publish:
//       in-order vmcnt retirement drains exactly the 2 dangling loads
//       (issued >= FMA-phase ago -> free) while the just-issued th/outs
//       stores stay outstanding -> publish never delayed.
//     - invariant: poll break always leaves exactly 2 loads in flight
//       (A-break -> B dangling; B-break -> re-armed A dangling); the
//       every-64-tries fallback drains to 0 and stays consistent.
//   Everything else byte-identical to v6 (same math order -> same absmax).
// ---------------------------------------------------------------------------
#define RING 8
#define UPB  8                 // units per block
#define NBLK (H / UPB)         // 128 blocks

#define POLL_ISSUE(x0, x1)                                              \
    asm volatile("global_load_dwordx2 %0, %2, off sc0 sc1\n\t"          \
                 "global_load_dwordx2 %1, %3, off sc0 sc1"              \
                 : "=&v"(x0), "=&v"(x1) : "v"(p0), "v"(p1) : "memory")

__global__ __launch_bounds__(512, 2) void gru_scan(
    const float* __restrict__ xu, const float* __restrict__ xr, const float* __restrict__ xc,
    const float* __restrict__ Wu, const float* __restrict__ Wr, const float* __restrict__ W,
    unsigned long long* __restrict__ th,  // RING*H tagged pairs (no init needed)
    float* __restrict__ out)              // d_out: [H h_final][SEQ*H outputs]
{
    // 96 KB weights + 8 KB hs = 104 KB LDS -> 1 block/CU
    __shared__ __align__(16) float4 wl[3 * UPB * 256];  // [mat][unit][k/4]
    __shared__ __align__(16) float hs[2][H];

    const int bid  = blockIdx.x;     // 0..127
    const int tid  = threadIdx.x;    // 0..511
    const int wid  = tid >> 6;       // 0..7
    const int lane = tid & 63;
    const int j    = bid * UPB + wid;     // hidden unit owned by this wave

    // ---- one-time: stage this block's weight rows into LDS --------------
    {
        const float4* src[3] = {
            (const float4*)(Wu + (size_t)bid * UPB * H),
            (const float4*)(Wr + (size_t)bid * UPB * H),
            (const float4*)(W  + (size_t)bid * UPB * H)};
        for (int idx = tid; idx < 3 * UPB * 256; idx += 512) {
            const int M = idx >> 11;          // /2048
            wl[idx] = src[M][idx & 2047];     // rows are contiguous per mat
        }
    }
    __syncthreads();

    float* outs = out + H;
    float hprev = 0.f;               // lane0: previous h[j]

    const float4* wu4 = &wl[(0 * UPB + wid) * 256];
    const float4* wr4 = &wl[(1 * UPB + wid) * 256];
    const float4* wc4 = &wl[(2 * UPB + wid) * 256];

    // staggered-poll sample registers (live across the FMA phase; reusable
    // only after the end-of-iteration counted drain)
    unsigned long long a0 = 0, a1 = 0, b0 = 0, b1 = 0;

    for (int t = 0; t < SEQ; t++) {
        // prefetch x-projections (latency hides under the poll)
        float axu = 0.f, axr = 0.f, axc = 0.f;
        if (lane == 0) {
            axu = xu[(size_t)t * H + j];
            axr = xr[(size_t)t * H + j];
            axc = xc[(size_t)t * H + j];
        }

        // issue weight ds_reads early: lgkmcnt is independent of the poll's
        // vmcnt, so these complete during the MALL round trip.
        float4 wu[4], wr[4], wc[4];
#pragma unroll
        for (int m = 0; m < 4; m++) {
            wu[m] = wu4[m * 64 + lane];
            wr[m] = wr4[m * 64 + lane];
            wc[m] = wc4[m * 64 + lane];
        }

        float* hb = hs[t & 1];
        if (t == 0) {
            hb[wid * 128 + lane]      = 0.f;   // h0 = 0, nothing to poll
            hb[wid * 128 + 64 + lane] = 0.f;
        } else {
            // wave w polls units [w*128, w*128+128) of slot (t&7) for tag t,
            // with two phase-shifted sample pairs in flight (period ~RT/2).
            const unsigned long long* p0 = th + (size_t)(t & (RING - 1)) * H
                                              + wid * 128 + lane;
            const unsigned long long* p1 = p0 + 64;
            unsigned long long v0, v1;
            POLL_ISSUE(a0, a1);                 // sample pair A
            POLL_ISSUE(b0, b1);                 // sample pair B (staggered)
            int tries = 0;
            for (;;) {
                asm volatile("s_waitcnt vmcnt(2)" ::: "memory");  // A landed
                __builtin_amdgcn_sched_barrier(0);
                if (__all(((int)(a0 >> 32) == t) & ((int)(a1 >> 32) == t))) {
                    v0 = a0; v1 = a1; break;    // B pair left dangling
                }
                POLL_ISSUE(a0, a1);             // re-arm A
                asm volatile("s_waitcnt vmcnt(2)" ::: "memory");  // B landed
                __builtin_amdgcn_sched_barrier(0);
                if (__all(((int)(b0 >> 32) == t) & ((int)(b1 >> 32) == t))) {
                    v0 = b0; v1 = b1; break;    // A pair left dangling
                }
                POLL_ISSUE(b0, b1);             // re-arm B
                if (((++tries) & 63) == 0) {
                    // safety net: guaranteed-correct compiler-emitted system
                    // loads (cold path; drains vmcnt -> 0 danglers, still
                    // consistent with the end-of-iteration vmcnt(2)).
                    unsigned long long c0 = __hip_atomic_load(p0, __ATOMIC_RELAXED, __HIP_MEMORY_SCOPE_SYSTEM);
                    unsigned long long c1 = __hip_atomic_load(p1, __ATOMIC_RELAXED, __HIP_MEMORY_SCOPE_SYSTEM);
                    if (__all(((int)(c0 >> 32) == t) & ((int)(c1 >> 32) == t))) {
                        v0 = c0; v1 = c1; break;
                    }
                }
            }
            hb[wid * 128 + lane]      = __uint_as_float((unsigned)v0);
            hb[wid * 128 + 64 + lane] = __uint_as_float((unsigned)v1);
        }

        // RAW barrier: drain LDS writes only (hb visibility); dangling poll
        // loads stay in flight across the barrier (the whole point of v8).
        asm volatile("s_waitcnt lgkmcnt(0)" ::: "memory");
        __builtin_amdgcn_sched_barrier(0);
        __builtin_amdgcn_s_barrier();

        const float4* hsl = (const float4*)hb;
        float au = 0.f, ar = 0.f, aw = 0.f;
#pragma unroll
        for (int m = 0; m < 4; m++) {
            float4 h = hsl[m * 64 + lane];
            au += wu[m].x * h.x + wu[m].y * h.y + wu[m].z * h.z + wu[m].w * h.w;
            ar += wr[m].x * h.x + wr[m].y * h.y + wr[m].z * h.z + wr[m].w * h.w;
            aw += wc[m].x * h.x + wc[m].y * h.y + wc[m].z * h.z + wc[m].w * h.w;
        }

#pragma unroll
        for (int off = 32; off > 0; off >>= 1) {
            au += __shfl_xor(au, off, 64);
            ar += __shfl_xor(ar, off, 64);
            aw += __shfl_xor(aw, off, 64);
        }

        if (lane == 0) {
            float u    = 1.f / (1.f + __expf(-(axu + au)));
            float r    = 1.f / (1.f + __expf(-(axr + ar)));
            float cand = 1.f / (1.f + __expf(-(axc + r * aw)));
            float hnew = u * hprev + (1.f - u) * cand;
            hprev = hnew;
            // publish (value, tag=t+1) in ONE 8B system-scope store
            unsigned long long pkt =
                ((unsigned long long)(unsigned)(t + 1) << 32) |
                (unsigned long long)__float_as_uint(hnew);
            unsigned long long* q = th + (size_t)((t + 1) & (RING - 1)) * H + j;
            __hip_atomic_store(q, pkt, __ATOMIC_RELAXED, __HIP_MEMORY_SCOPE_SYSTEM);
            outs[(size_t)t * H + j] = hnew;       // plain cached store
            if (t == SEQ - 1) out[j] = hnew;      // h_final
        }

        // counted drain AFTER the publish: in-order retirement drains the 2
        // dangling poll loads (issued >= FMA-phase ago -> free) and leaves
        // the newest 2 VMEM ops (th + outs stores) outstanding -> the
        // publish is never delayed. Keep-alive pins a0..b1 until landed.
        asm volatile("s_waitcnt vmcnt(2)" ::: "memory");
        __builtin_amdgcn_sched_barrier(0);
        asm volatile("" :: "v"(a0), "v"(a1), "v"(b0), "v"(b1));
        // no trailing barrier: next step stages into the other hs buffer;
        // buffer reuse is gated by the NEXT step's barrier.
    }
}

// ---------------------------------------------------------------------------
extern "C" void kernel_launch(void* const* d_in, const int* in_sizes, int n_in,
                              void* d_out, int out_size, void* d_ws, size_t ws_size,
                              hipStream_t stream) {
    const float* x  = (const float*)d_in[0];
    const float* Uu = (const float*)d_in[1];
    const float* Wu = (const float*)d_in[2];
    const float* Bu = (const float*)d_in[3];
    const float* Ur = (const float*)d_in[4];
    const float* Wr = (const float*)d_in[5];
    const float* Br = (const float*)d_in[6];
    const float* U  = (const float*)d_in[7];
    const float* W  = (const float*)d_in[8];
    const float* B  = (const float*)d_in[9];

    char* ws = (char*)d_ws;
    const size_t MAT = (size_t)SEQ * H * sizeof(float);  // 32 MB
    float* xu = (float*)(ws);
    float* xr = (float*)(ws + MAT);
    float* xc = (float*)(ws + 2 * MAT);
    unsigned long long* th = (unsigned long long*)(ws + 3 * MAT);  // 64 KB ring

    dim3 g(H / 64, SEQ / 64, 3);
    proj_gemm<<<g, 256, 0, stream>>>(x, Uu, Bu, xu, Ur, Br, xr, U, B, xc);

    gru_scan<<<NBLK, 512, 0, stream>>>(xu, xr, xc, Wu, Wr, W, th, (float*)d_out);
}

// Round 10
// 14206.657 us; speedup vs baseline: 1.0822x; 1.0822x over previous
//
#include <hip/hip_runtime.h>

#define SEQ 8192
#define H 1024

// ---------------------------------------------------------------------------
// Projection GEMM (NT): C[i][j] = bias[j] + sum_k A[i][k]*B[j][k]
// (unchanged — ~0.6 ms, not the bottleneck)
// ---------------------------------------------------------------------------
#define KC 32
#define LDT 68

__global__ __launch_bounds__(256) void proj_gemm(
    const float* __restrict__ A,
    const float* __restrict__ B0, const float* __restrict__ b0, float* __restrict__ C0,
    const float* __restrict__ B1, const float* __restrict__ b1, float* __restrict__ C1,
    const float* __restrict__ B2, const float* __restrict__ b2, float* __restrict__ C2)
{
    __shared__ __align__(16) float As[KC * LDT];
    __shared__ __align__(16) float Bs[KC * LDT];

    const float* Bm; const float* bias; float* C;
    if (blockIdx.z == 0)      { Bm = B0; bias = b0; C = C0; }
    else if (blockIdx.z == 1) { Bm = B1; bias = b1; C = C1; }
    else                      { Bm = B2; bias = b2; C = C2; }

    const int j0 = blockIdx.x * 64;
    const int i0 = blockIdx.y * 64;
    const int tid = threadIdx.x;
    const int tx = tid & 15, ty = tid >> 4;
    const int lrow = tid >> 3;
    const int lkq  = tid & 7;

    float acc[4][4];
#pragma unroll
    for (int r = 0; r < 4; r++)
#pragma unroll
        for (int c = 0; c < 4; c++) acc[r][c] = 0.f;

    for (int k0 = 0; k0 < H; k0 += KC) {
#pragma unroll
        for (int half = 0; half < 2; half++) {
            const int row = lrow + half * 32;
            float4 a = *(const float4*)&A[(size_t)(i0 + row) * H + k0 + 4 * lkq];
            As[(4 * lkq + 0) * LDT + row] = a.x;
            As[(4 * lkq + 1) * LDT + row] = a.y;
            As[(4 * lkq + 2) * LDT + row] = a.z;
            As[(4 * lkq + 3) * LDT + row] = a.w;
            float4 b = *(const float4*)&Bm[(size_t)(j0 + row) * H + k0 + 4 * lkq];
            Bs[(4 * lkq + 0) * LDT + row] = b.x;
            Bs[(4 * lkq + 1) * LDT + row] = b.y;
            Bs[(4 * lkq + 2) * LDT + row] = b.z;
            Bs[(4 * lkq + 3) * LDT + row] = b.w;
        }
        __syncthreads();
#pragma unroll
        for (int k = 0; k < KC; k++) {
            float4 a4 = *(const float4*)&As[k * LDT + ty * 4];
            float4 b4 = *(const float4*)&Bs[k * LDT + tx * 4];
            acc[0][0] += a4.x * b4.x; acc[0][1] += a4.x * b4.y;
            acc[0][2] += a4.x * b4.z; acc[0][3] += a4.x * b4.w;
            acc[1][0] += a4.y * b4.x; acc[1][1] += a4.y * b4.y;
            acc[1][2] += a4.y * b4.z; acc[1][3] += a4.y * b4.w;
            acc[2][0] += a4.z * b4.x; acc[2][1] += a4.z * b4.y;
            acc[2][2] += a4.z * b4.z; acc[2][3] += a4.z * b4.w;
            acc[3][0] += a4.w * b4.x; acc[3][1] += a4.w * b4.y;
            acc[3][2] += a4.w * b4.z; acc[3][3] += a4.w * b4.w;
        }
        __syncthreads();
    }

    float4 bi = *(const float4*)&bias[j0 + tx * 4];
#pragma unroll
    for (int r = 0; r < 4; r++) {
        float4 o;
        o.x = acc[r][0] + bi.x; o.y = acc[r][1] + bi.y;
        o.z = acc[r][2] + bi.z; o.w = acc[r][3] + bi.w;
        *(float4*)&C[(size_t)(i0 + ty * 4 + r) * H + j0 + tx * 4] = o;
    }
}

// ---------------------------------------------------------------------------
// GRU scan v9 = v6 (weights in LDS, proven 13.5 ms fast-mode) + paired-slot
// single-dwordx4 poll.
//   v7/v8 post-mortem: BOTH staggered-poll variants cost +1.1 ms regardless
//   of drain placement — re-arms issue ~20cy (not RT/2) after a failed
//   check, so sampling stayed RT-periodic with 2x the poll instructions.
//   Lesson: the consumer side is sensitive to poll WORK, not poll phase.
//   v9 goes the other way: lane l polls two ADJACENT slots
//   (wid*128 + 2l, +2l+1) -> one aligned 16B global_load_dwordx4 per retry
//   instead of two dwordx2 (half the VMEM ops, half the MALL requests, one
//   coalesced 1KB burst per wave-sample). 8B slot atomicity is preserved:
//   the producer's 8B store hits the cache line once; a 16B read of that
//   line cannot tear an 8B slot (same assumption v3/v6 already make).
//   LDS staging: one float2 store to the SAME hb addresses -> the FMA phase
//   reads identical values in identical order -> bit-identical numerics.
//   Everything else byte-identical to v6.
// ---------------------------------------------------------------------------
#define RING 8
#define UPB  8                 // units per block
#define NBLK (H / UPB)         // 128 blocks

typedef unsigned uint4v __attribute__((ext_vector_type(4)));

__global__ __launch_bounds__(512, 2) void gru_scan(
    const float* __restrict__ xu, const float* __restrict__ xr, const float* __restrict__ xc,
    const float* __restrict__ Wu, const float* __restrict__ Wr, const float* __restrict__ W,
    unsigned long long* __restrict__ th,  // RING*H tagged pairs (no init needed)
    float* __restrict__ out)              // d_out: [H h_final][SEQ*H outputs]
{
    // 96 KB weights + 8 KB hs = 104 KB LDS -> 1 block/CU
    __shared__ __align__(16) float4 wl[3 * UPB * 256];  // [mat][unit][k/4]
    __shared__ __align__(16) float hs[2][H];

    const int bid  = blockIdx.x;     // 0..127
    const int tid  = threadIdx.x;    // 0..511
    const int wid  = tid >> 6;       // 0..7
    const int lane = tid & 63;
    const int j    = bid * UPB + wid;     // hidden unit owned by this wave

    // ---- one-time: stage this block's weight rows into LDS --------------
    {
        const float4* src[3] = {
            (const float4*)(Wu + (size_t)bid * UPB * H),
            (const float4*)(Wr + (size_t)bid * UPB * H),
            (const float4*)(W  + (size_t)bid * UPB * H)};
        for (int idx = tid; idx < 3 * UPB * 256; idx += 512) {
            const int M = idx >> 11;          // /2048
            wl[idx] = src[M][idx & 2047];     // rows are contiguous per mat
        }
    }
    __syncthreads();

    float* outs = out + H;
    float hprev = 0.f;               // lane0: previous h[j]

    const float4* wu4 = &wl[(0 * UPB + wid) * 256];
    const float4* wr4 = &wl[(1 * UPB + wid) * 256];
    const float4* wc4 = &wl[(2 * UPB + wid) * 256];

    for (int t = 0; t < SEQ; t++) {
        // prefetch x-projections (latency hides under the poll)
        float axu = 0.f, axr = 0.f, axc = 0.f;
        if (lane == 0) {
            axu = xu[(size_t)t * H + j];
            axr = xr[(size_t)t * H + j];
            axc = xc[(size_t)t * H + j];
        }

        // issue weight ds_reads early: lgkmcnt is independent of the poll's
        // vmcnt, so these complete during the MALL round trip.
        float4 wu[4], wr[4], wc[4];
#pragma unroll
        for (int m = 0; m < 4; m++) {
            wu[m] = wu4[m * 64 + lane];
            wr[m] = wr4[m * 64 + lane];
            wc[m] = wc4[m * 64 + lane];
        }

        float* hb = hs[t & 1];
        if (t == 0) {
            hb[wid * 128 + lane]      = 0.f;   // h0 = 0, nothing to poll
            hb[wid * 128 + 64 + lane] = 0.f;
        } else {
            // lane l polls adjacent slots wid*128 + 2l, +2l+1 of slot ring
            // (t&7) for tag t: ONE aligned 16B load = both (val,tag) pairs.
            const unsigned long long* pb = th + (size_t)(t & (RING - 1)) * H
                                              + wid * 128 + 2 * lane;
            uint4v q;
            int tries = 0;
            for (;;) {
                asm volatile("global_load_dwordx4 %0, %1, off sc0 sc1\n\t"
                             "s_waitcnt vmcnt(0)"
                             : "=&v"(q) : "v"(pb) : "memory");
                __builtin_amdgcn_sched_barrier(0);
                if (__all((q[1] == (unsigned)t) & (q[3] == (unsigned)t))) break;
                if (((++tries) & 63) == 0) {
                    // safety net: guaranteed-correct compiler-emitted system
                    // loads (cold path; prevents livelock if the asm cache
                    // flags were ever stale-served).
                    unsigned long long c0 = __hip_atomic_load(pb,     __ATOMIC_RELAXED, __HIP_MEMORY_SCOPE_SYSTEM);
                    unsigned long long c1 = __hip_atomic_load(pb + 1, __ATOMIC_RELAXED, __HIP_MEMORY_SCOPE_SYSTEM);
                    if (__all(((int)(c0 >> 32) == t) & ((int)(c1 >> 32) == t))) {
                        q[0] = (unsigned)c0; q[2] = (unsigned)c1;
                        break;
                    }
                }
            }
            // stage both values with one 8B LDS store to the SAME addresses
            // v6 used -> FMA phase reads identical data.
            ((float2*)hb)[wid * 64 + lane] =
                make_float2(__uint_as_float(q[0]), __uint_as_float(q[2]));
        }
        __syncthreads();   // the ONLY barrier per step (hs double-buffered)

        const float4* hsl = (const float4*)hb;
        float au = 0.f, ar = 0.f, aw = 0.f;
#pragma unroll
        for (int m = 0; m < 4; m++) {
            float4 h = hsl[m * 64 + lane];
            au += wu[m].x * h.x + wu[m].y * h.y + wu[m].z * h.z + wu[m].w * h.w;
            ar += wr[m].x * h.x + wr[m].y * h.y + wr[m].z * h.z + wr[m].w * h.w;
            aw += wc[m].x * h.x + wc[m].y * h.y + wc[m].z * h.z + wc[m].w * h.w;
        }

#pragma unroll
        for (int off = 32; off > 0; off >>= 1) {
            au += __shfl_xor(au, off, 64);
            ar += __shfl_xor(ar, off, 64);
            aw += __shfl_xor(aw, off, 64);
        }

        if (lane == 0) {
            float u    = 1.f / (1.f + __expf(-(axu + au)));
            float r    = 1.f / (1.f + __expf(-(axr + ar)));
            float cand = 1.f / (1.f + __expf(-(axc + r * aw)));
            float hnew = u * hprev + (1.f - u) * cand;
            hprev = hnew;
            // publish (value, tag=t+1) in ONE 8B system-scope store
            unsigned long long pkt =
                ((unsigned long long)(unsigned)(t + 1) << 32) |
                (unsigned long long)__float_as_uint(hnew);
            unsigned long long* q8 = th + (size_t)((t + 1) & (RING - 1)) * H + j;
            __hip_atomic_store(q8, pkt, __ATOMIC_RELAXED, __HIP_MEMORY_SCOPE_SYSTEM);
            outs[(size_t)t * H + j] = hnew;       // plain cached store
            if (t == SEQ - 1) out[j] = hnew;      // h_final
        }
        // no trailing barrier: next step stages into the other hs buffer;
        // buffer reuse is gated by the NEXT step's barrier.
    }
}

// ---------------------------------------------------------------------------
extern "C" void kernel_launch(void* const* d_in, const int* in_sizes, int n_in,
                              void* d_out, int out_size, void* d_ws, size_t ws_size,
                              hipStream_t stream) {
    const float* x  = (const float*)d_in[0];
    const float* Uu = (const float*)d_in[1];
    const float* Wu = (const float*)d_in[2];
    const float* Bu = (const float*)d_in[3];
    const float* Ur = (const float*)d_in[4];
    const float* Wr = (const float*)d_in[5];
    const float* Br = (const float*)d_in[6];
    const float* U  = (const float*)d_in[7];
    const float* W  = (const float*)d_in[8];
    const float* B  = (const float*)d_in[9];

    char* ws = (char*)d_ws;
    const size_t MAT = (size_t)SEQ * H * sizeof(float);  // 32 MB
    float* xu = (float*)(ws);
    float* xr = (float*)(ws + MAT);
    float* xc = (float*)(ws + 2 * MAT);
    unsigned long long* th = (unsigned long long*)(ws + 3 * MAT);  // 64 KB ring

    dim3 g(H / 64, SEQ / 64, 3);
    proj_gemm<<<g, 256, 0, stream>>>(x, Uu, Bu, xu, Ur, Br, xr, U, B, xc);

    gru_scan<<<NBLK, 512, 0, stream>>>(xu, xr, xc, Wu, Wr, W, th, (float*)d_out);
}